// Round 11
// baseline (84.867 us; speedup 1.0000x reference)
//
#include <hip/hip_runtime.h>
#include <hip/hip_bf16.h>

// Problem constants (reference: N=2048, D=512, T=0.1, sigma=1, 4 classes)
#define D 512
#define INV_T 10.0f
#define INF_VAL 1e8f

#define BM 128
#define BK 32
#define KSTEPS (D / BK)   // 16
#define NTB 32            // 4096/128 tiles per dim
#define NGB (NTB * NTB)   // 1024 full-matrix gemm blocks (4 per CU)
#define TTBLK 128         // tt-role blocks appended at grid tail (R9-proven)
#define NCHUNK 64         // 64-wide column chunks for partials

typedef short bf16x8 __attribute__((ext_vector_type(8)));
typedef float f32x4 __attribute__((ext_vector_type(4)));

typedef __attribute__((address_space(3))) unsigned int lds_uint;
typedef __attribute__((address_space(1))) unsigned int gbl_uint;

__device__ __forceinline__ void async_copy16(const ushort* gsrc, ushort* ldst) {
  // 64 lanes x 16B -> 1 KB; LDS dest = wave-uniform base + lane*16 (linear)
  __builtin_amdgcn_global_load_lds((const gbl_uint*)gsrc, (lds_uint*)ldst, 16, 0, 0);
}

__device__ inline float wave_reduce_sum(float v) {
#pragma unroll
  for (int off = 32; off > 0; off >>= 1) v += __shfl_xor(v, off);
  return v;
}

__device__ __forceinline__ ushort f2bf(float x) {
  __hip_bfloat16 h = __float2bfloat16(x);
  return *reinterpret_cast<ushort*>(&h);
}

// -------------------------------------------------------------------------
// Fused prep (proven R8/R9):
//   blocks [0,1024):    normalize+cast zb (wave-per-row, 4 rows/block)
//   blocks [1024,3072): sinv[j] = 1/(2*shalf[j]-1)
__global__ __launch_bounds__(256) void k_prep(const float* __restrict__ zi,
                                              const float* __restrict__ zj,
                                              ushort* __restrict__ zb,
                                              const int* __restrict__ labels,
                                              const float* __restrict__ zpos,
                                              float* __restrict__ sinv, int N) {
  int b = blockIdx.x;
  if (b < 1024) {
    int wv = threadIdx.x >> 6, lane = threadIdx.x & 63;
    int row = b * 4 + wv;
    const float* src = (row < N) ? (zi + (size_t)row * D) : (zj + (size_t)(row - N) * D);
    const float4* s4 = reinterpret_cast<const float4*>(src);
    float4 v0 = s4[lane];
    float4 v1 = s4[lane + 64];
    float ss = 0.f;
    ss = fmaf(v0.x, v0.x, ss); ss = fmaf(v0.y, v0.y, ss);
    ss = fmaf(v0.z, v0.z, ss); ss = fmaf(v0.w, v0.w, ss);
    ss = fmaf(v1.x, v1.x, ss); ss = fmaf(v1.y, v1.y, ss);
    ss = fmaf(v1.z, v1.z, ss); ss = fmaf(v1.w, v1.w, ss);
    ss = wave_reduce_sum(ss);
    float sc = 1.0f / fmaxf(sqrtf(ss), 1e-12f);
    ushort4 o0 = {f2bf(v0.x * sc), f2bf(v0.y * sc), f2bf(v0.z * sc), f2bf(v0.w * sc)};
    ushort4 o1 = {f2bf(v1.x * sc), f2bf(v1.y * sc), f2bf(v1.z * sc), f2bf(v1.w * sc)};
    ushort4* dst = reinterpret_cast<ushort4*>(zb + (size_t)row * D);
    dst[lane] = o0;
    dst[lane + 64] = o1;
  } else {
    __shared__ float scratch[4];
    int j = b - 1024;
    int lj = labels[j];
    float pj = zpos[j];
    float s = 0.f;
    for (int i = threadIdx.x; i < N; i += 256) {
      if (labels[i] == lj) {
        float d = zpos[i] - pj;
        s += __expf(-0.5f * d * d);
      }
    }
    s = wave_reduce_sum(s);
    int lane = threadIdx.x & 63, wv = threadIdx.x >> 6;
    if (lane == 0) scratch[wv] = s;
    __syncthreads();
    if (threadIdx.x == 0) {
      float t = scratch[0] + scratch[1] + scratch[2] + scratch[3];
      sinv[j] = 1.0f / (2.0f * t - 1.0f);
    }
  }
}

// -------------------------------------------------------------------------
// Main GEMM. Blocks [0,1024): FULL-matrix 128x128 tiles (R5-bench geometry:
// the measured-best 40 ns/tile config — 4 grid-blocks/CU is the latency
// hider). 4 waves (2x2), each a 64x64 quadrant. BK=32 with double-buffered
// 2x16 KB LDS (R6/R9-proven prefetch->compute->sync, LDS total unchanged at
// 32 KB so blocks/CU is NOT reduced). Staging swizzle = R10's 64B-row pair
// (measured 0 conflicts): linear LDS dest, source slot pre-XORed with
// (row>>1)&3, ds_read XORs the same key (rule #21 both-sides pair).
// Forward-only epilogue: fixed-max softmax (sim = 10*cos <= 10) exp-sum +
// label/RBF-weighted cross; partials at chunk m = ct*2 + wc.
// Blocks [1024,1152): tt[i] = sum_j same(i,j)*rbf(i,j)*sinv[j] (R9-proven).
__global__ __launch_bounds__(256, 4) void k_gemm(
    const ushort* __restrict__ zb, const int* __restrict__ labels,
    const float* __restrict__ zpos, const float* __restrict__ sinv,
    float* __restrict__ tt,
    float* __restrict__ s_ws, float* __restrict__ c_ws, int N) {
  const int tid = threadIdx.x;
  const int bid = blockIdx.x;
  const int twoN = 2 * N;

  if (bid >= NGB) {
    // ---- tt role: 16 rows/block, 16 threads/row ----
    int i = (bid - NGB) * 16 + (tid >> 4);
    int part = tid & 15;
    int li = labels[i];
    float pi = zpos[i];
    int seg = N >> 4;              // 128
    float s = 0.f;
    for (int j = part * seg; j < (part + 1) * seg; ++j) {
      if (labels[j] == li) {
        float d = zpos[j] - pi;
        s += __expf(-0.5f * d * d) * sinv[j];
      }
    }
    s += __shfl_xor(s, 1); s += __shfl_xor(s, 2);
    s += __shfl_xor(s, 4); s += __shfl_xor(s, 8);
    if (part == 0) tt[i] = s;
    return;
  }

  __shared__ __align__(16) ushort As[2][BM * BK];   // 2 x 8 KB
  __shared__ __align__(16) ushort Bs[2][BM * BK];   // 2 x 8 KB

  const int lane = tid & 63;
  const int wv = tid >> 6;        // 0..3
  const int wr = wv >> 1;         // row half
  const int wc = wv & 1;          // col half
  const int colq = lane & 15;
  const int laneg = lane >> 4;

  // XCD swizzle (1024 % 8 == 0 -> bijective)
  const int L = (bid & 7) * 128 + (bid >> 3);
  const int rt = L >> 5;          // 0..31
  const int ct = L & 31;          // 0..31
  const int rowBase = rt * BM;
  const int colBase = ct * BM;

  // staging: 1 inst = 16 rows x 64B (4 slots of 16B). lane -> row lane>>2,
  // phys slot lane&3. Source slot pre-XORed with (row>>1)&3 == (lane>>3)&3.
  const int srow = lane >> 2;                        // 0..15
  const int sslot = (lane & 3) ^ ((lane >> 3) & 3);  // R10-proven pair

  f32x4 acc[4][4] = {};

  // each wave stages A rows [wv*32,+32) and B rows [wv*32,+32): 4 insts/step
#define STAGE(buf, kt)                                                        \
  {                                                                           \
    _Pragma("unroll")                                                         \
    for (int q = 0; q < 2; ++q) {                                             \
      int r0 = wv * 32 + q * 16;                                              \
      async_copy16(zb + (size_t)(rowBase + r0 + srow) * D + (kt) * BK +       \
                       sslot * 8,                                             \
                   As[buf] + r0 * BK);                                        \
      async_copy16(zb + (size_t)(colBase + r0 + srow) * D + (kt) * BK +       \
                       sslot * 8,                                             \
                   Bs[buf] + r0 * BK);                                        \
    }                                                                         \
  }

  STAGE(0, 0);
  __syncthreads();

  int cur = 0;
#pragma unroll
  for (int kt = 0; kt < KSTEPS; ++kt) {
    if (kt + 1 < KSTEPS) STAGE(cur ^ 1, kt + 1);   // prefetch overlaps compute

    const char* Ab = reinterpret_cast<const char*>(As[cur]);
    const char* Bb = reinterpret_cast<const char*>(Bs[cur]);
    bf16x8 a[4], b[4];
#pragma unroll
    for (int rf = 0; rf < 4; ++rf) {
      int r = wr * 64 + rf * 16 + colq;
      a[rf] = *reinterpret_cast<const bf16x8*>(
          Ab + r * 64 + ((laneg ^ ((r >> 1) & 3)) << 4));
    }
#pragma unroll
    for (int cf = 0; cf < 4; ++cf) {
      int c = wc * 64 + cf * 16 + colq;
      b[cf] = *reinterpret_cast<const bf16x8*>(
          Bb + c * 64 + ((laneg ^ ((c >> 1) & 3)) << 4));
    }
#pragma unroll
    for (int rf = 0; rf < 4; ++rf)
#pragma unroll
      for (int cf = 0; cf < 4; ++cf)
        acc[rf][cf] = __builtin_amdgcn_mfma_f32_16x16x32_bf16(a[rf], b[cf], acc[rf][cf], 0, 0, 0);

    if (kt + 1 < KSTEPS) {
      __syncthreads();   // prefetch landed (vmcnt drained) + reads done
      cur ^= 1;
    }
  }
#undef STAGE

  // ---- epilogue (forward only; verbatim R5-bench) ----
  // C layout: col = lane&15, row = (lane>>4)*4 + reg  [m89 verified]
  const int wRowBase = rowBase + wr * 64;
  const int wColBase = colBase + wc * 64;
  const int rmodBase = (wRowBase >= N) ? wRowBase - N : wRowBase;
  const int cmodBase = (wColBase >= N) ? wColBase - N : wColBase;

  float rpos[16];
  unsigned rlab = 0;
#pragma unroll
  for (int rf = 0; rf < 4; ++rf)
#pragma unroll
    for (int rg = 0; rg < 4; ++rg) {
      int idx = rf * 4 + rg;
      int r = rmodBase + rf * 16 + laneg * 4 + rg;
      rpos[idx] = zpos[r];
      rlab |= ((unsigned)labels[r] & 3u) << (idx * 2);
    }

  float s_p[16], c_p[16];
#pragma unroll
  for (int i = 0; i < 16; ++i) { s_p[i] = 0.f; c_p[i] = 0.f; }

#pragma unroll
  for (int cf = 0; cf < 4; ++cf) {
    int jc = cmodBase + cf * 16 + colq;
    int lc = labels[jc];
    float pc = zpos[jc];
    float si = sinv[jc];
    int col = wColBase + cf * 16 + colq;
#pragma unroll
    for (int rf = 0; rf < 4; ++rf)
#pragma unroll
      for (int rg = 0; rg < 4; ++rg) {
        int idx = rf * 4 + rg;
        int row = wRowBase + rf * 16 + laneg * 4 + rg;
        float sim = acc[rf][cf][rg] * INV_T;
        bool dg = (row == col);
        if (dg) sim = -INF_VAL;
        s_p[idx] += __expf(sim - 10.f);        // exp(-1e8)==0: diag drops out
        int lr = (int)((rlab >> (idx * 2)) & 3u);
        if (lr == lc && !dg) {
          float d = rpos[idx] - pc;
          c_p[idx] = fmaf(__expf(-0.5f * d * d) * si, sim, c_p[idx]);
        }
      }
  }

  // reduce each row over the 16 lanes sharing it
#pragma unroll
  for (int idx = 0; idx < 16; ++idx) {
#pragma unroll
    for (int off = 1; off < 16; off <<= 1) {
      s_p[idx] += __shfl_xor(s_p[idx], off);
      c_p[idx] += __shfl_xor(c_p[idx], off);
    }
  }
  if (colq == 0) {
    int m = ct * 2 + wc;      // 64-wide column chunk index
#pragma unroll
    for (int rf = 0; rf < 4; ++rf)
#pragma unroll
      for (int rg = 0; rg < 4; ++rg) {
        int idx = rf * 4 + rg;
        int row = wRowBase + rf * 16 + laneg * 4 + rg;
        s_ws[(size_t)m * twoN + row] = s_p[idx];
        c_ws[(size_t)m * twoN + row] = c_p[idx];
      }
  }
}

// -------------------------------------------------------------------------
// Per-row combine + block partial sum (proven R8/R9, NCHUNK=64 slots).
// 64 blocks x 64 rows. partial[a] = cross_a - wsum_a*(10 + log(sum_m s_ws))
__global__ __launch_bounds__(256) void k_combine(const float* __restrict__ s_ws,
                                                 const float* __restrict__ c_ws,
                                                 const float* __restrict__ sinv,
                                                 const float* __restrict__ tt,
                                                 float* __restrict__ bsum, int N) {
  __shared__ float sS[4][64], sC[4][64];
  int b = blockIdx.x, t = threadIdx.x;
  int r = t & 63, g = t >> 6;
  int twoN = 2 * N;
  int a = b * 64 + r;
  float s = 0.f, c = 0.f;
  for (int k = 0; k < NCHUNK / 4; ++k) {
    int m = g * (NCHUNK / 4) + k;
    s += s_ws[(size_t)m * twoN + a];
    c += c_ws[(size_t)m * twoN + a];
  }
  sS[g][r] = s;
  sC[g][r] = c;
  __syncthreads();
  if (t < 64) {
    float st = sS[0][t] + sS[1][t] + sS[2][t] + sS[3][t];
    float ct = sC[0][t] + sC[1][t] + sC[2][t] + sC[3][t];
    int aa = b * 64 + t;
    int ir = (aa >= N) ? aa - N : aa;
    float lse = 10.f + logf(st);
    float wsum = 2.f * tt[ir] - sinv[ir];
    float p = ct - wsum * lse;
    p = wave_reduce_sum(p);
    if (t == 0) bsum[b] = p;
  }
}

// loss = (-1/N) * sum_b bsum[b]
__global__ __launch_bounds__(64) void k_final(const float* __restrict__ bsum,
                                              float* __restrict__ out, int N) {
  float s = bsum[threadIdx.x];
  s = wave_reduce_sum(s);
  if (threadIdx.x == 0) out[0] = (-1.0f / (float)N) * s;
}

extern "C" void kernel_launch(void* const* d_in, const int* in_sizes, int n_in,
                              void* d_out, int out_size, void* d_ws, size_t ws_size,
                              hipStream_t stream) {
  (void)n_in; (void)out_size; (void)ws_size;
  const float* zi = (const float*)d_in[0];
  const float* zj = (const float*)d_in[1];
  const int* labels = (const int*)d_in[2];
  const float* zpos = (const float*)d_in[3];
  float* out = (float*)d_out;

  const int N = in_sizes[2];       // 2048
  const int twoN = 2 * N;

  // workspace: zb bf16[2N*D] | sinv[N] | tt[N] | s_ws[64*2N] | c_ws[64*2N] | bsum[64]
  char* wsb = (char*)d_ws;
  ushort* zb = (ushort*)wsb;                              // 4 MB
  float* sinv = (float*)(wsb + (size_t)twoN * D * 2);
  float* tt = sinv + N;
  float* s_ws = tt + N;                                   // 1 MB
  float* c_ws = s_ws + (size_t)NCHUNK * twoN;             // 1 MB
  float* bsum = c_ws + (size_t)NCHUNK * twoN;

  k_prep<<<1024 + 2048, 256, 0, stream>>>(zi, zj, zb, labels, zpos, sinv, N);
  k_gemm<<<NGB + TTBLK, 256, 0, stream>>>(zb, labels, zpos, sinv, tt, s_ws, c_ws, N);
  k_combine<<<twoN / 64, 256, 0, stream>>>(s_ws, c_ws, sinv, tt, bsum, N);
  k_final<<<1, 64, 0, stream>>>(bsum, out, N);
}

// Round 12
// 70.537 us; speedup vs baseline: 1.2032x; 1.2032x over previous
//
#include <hip/hip_runtime.h>
#include <hip/hip_bf16.h>

// Problem constants (reference: N=2048, D=512, T=0.1, sigma=1, 4 classes)
#define D 512
#define INV_T 10.0f
#define INF_VAL 1e8f

#define BM 128
#define BK 64
#define KSTEPS (D / BK)   // 8
#define NTB 32            // 4096/128 tiles per dim
#define NGB (NTB * NTB)   // 1024 full-matrix gemm blocks
#define TTBLK 128         // tt-role blocks at grid tail (R9/R10/R11-proven)
#define NCHUNK 64         // 64-wide column chunks for partials

typedef short bf16x8 __attribute__((ext_vector_type(8)));
typedef float f32x4 __attribute__((ext_vector_type(4)));

typedef __attribute__((address_space(3))) unsigned int lds_uint;
typedef __attribute__((address_space(1))) unsigned int gbl_uint;

__device__ __forceinline__ void async_copy16(const ushort* gsrc, ushort* ldst) {
  // 64 lanes x 16B -> 1 KB; LDS dest = wave-uniform base + lane*16 (linear)
  __builtin_amdgcn_global_load_lds((const gbl_uint*)gsrc, (lds_uint*)ldst, 16, 0, 0);
}

__device__ inline float wave_reduce_sum(float v) {
#pragma unroll
  for (int off = 32; off > 0; off >>= 1) v += __shfl_xor(v, off);
  return v;
}

__device__ __forceinline__ ushort f2bf(float x) {
  __hip_bfloat16 h = __float2bfloat16(x);
  return *reinterpret_cast<ushort*>(&h);
}

// -------------------------------------------------------------------------
// Fused prep (proven R5..R11):
//   blocks [0,1024):    normalize+cast zb (wave-per-row, 4 rows/block)
//   blocks [1024,3072): sinv[j] = 1/(2*shalf[j]-1)
__global__ __launch_bounds__(256) void k_prep(const float* __restrict__ zi,
                                              const float* __restrict__ zj,
                                              ushort* __restrict__ zb,
                                              const int* __restrict__ labels,
                                              const float* __restrict__ zpos,
                                              float* __restrict__ sinv, int N) {
  int b = blockIdx.x;
  if (b < 1024) {
    int wv = threadIdx.x >> 6, lane = threadIdx.x & 63;
    int row = b * 4 + wv;
    const float* src = (row < N) ? (zi + (size_t)row * D) : (zj + (size_t)(row - N) * D);
    const float4* s4 = reinterpret_cast<const float4*>(src);
    float4 v0 = s4[lane];
    float4 v1 = s4[lane + 64];
    float ss = 0.f;
    ss = fmaf(v0.x, v0.x, ss); ss = fmaf(v0.y, v0.y, ss);
    ss = fmaf(v0.z, v0.z, ss); ss = fmaf(v0.w, v0.w, ss);
    ss = fmaf(v1.x, v1.x, ss); ss = fmaf(v1.y, v1.y, ss);
    ss = fmaf(v1.z, v1.z, ss); ss = fmaf(v1.w, v1.w, ss);
    ss = wave_reduce_sum(ss);
    float sc = 1.0f / fmaxf(sqrtf(ss), 1e-12f);
    ushort4 o0 = {f2bf(v0.x * sc), f2bf(v0.y * sc), f2bf(v0.z * sc), f2bf(v0.w * sc)};
    ushort4 o1 = {f2bf(v1.x * sc), f2bf(v1.y * sc), f2bf(v1.z * sc), f2bf(v1.w * sc)};
    ushort4* dst = reinterpret_cast<ushort4*>(zb + (size_t)row * D);
    dst[lane] = o0;
    dst[lane + 64] = o1;
  } else {
    __shared__ float scratch[4];
    int j = b - 1024;
    int lj = labels[j];
    float pj = zpos[j];
    float s = 0.f;
    for (int i = threadIdx.x; i < N; i += 256) {
      if (labels[i] == lj) {
        float d = zpos[i] - pj;
        s += __expf(-0.5f * d * d);
      }
    }
    s = wave_reduce_sum(s);
    int lane = threadIdx.x & 63, wv = threadIdx.x >> 6;
    if (lane == 0) scratch[wv] = s;
    __syncthreads();
    if (threadIdx.x == 0) {
      float t = scratch[0] + scratch[1] + scratch[2] + scratch[3];
      sinv[j] = 1.0f / (2.0f * t - 1.0f);
    }
  }
}

// -------------------------------------------------------------------------
// Main GEMM — the R4 kernel (measured 41 us, the best of 8 configs) with
// EXACTLY ONE change: a 2D XCD swizzle. Each XCD owns a 16rt x 8ct region
// of the 32x32 tile grid -> per-XCD footprint = A 2 MB + B 1 MB = 3 MB,
// which FITS the 4 MB per-XCD L2 (the 1D %8 swizzle needed 4.5 MB and
// thrashed: FETCH_SIZE 36.8 MB == 8 x 4.5 MB compulsory).
// Structure (verbatim R4): 128x128 tile, BK=64, single-buffered 32 KB LDS,
// stage -> sync -> compute -> sync; 4 waves (2x2), each a 64x64 quadrant;
// linear LDS dest + pre-swizzled source slot (lane&7)^(lane>>3), read-side
// XOR slot^(r&7) (rule #21 pair, measured 0 conflicts).
// Blocks [1024,1152): tt[i] = sum_j same(i,j)*rbf(i,j)*sinv[j] (R9-proven).
__global__ __launch_bounds__(256, 4) void k_gemm(
    const ushort* __restrict__ zb, const int* __restrict__ labels,
    const float* __restrict__ zpos, const float* __restrict__ sinv,
    float* __restrict__ tt,
    float* __restrict__ s_ws, float* __restrict__ c_ws, int N) {
  const int tid = threadIdx.x;
  const int bid = blockIdx.x;
  const int twoN = 2 * N;

  if (bid >= NGB) {
    // ---- tt role: 16 rows/block, 16 threads/row ----
    int i = (bid - NGB) * 16 + (tid >> 4);
    int part = tid & 15;
    int li = labels[i];
    float pi = zpos[i];
    int seg = N >> 4;              // 128
    float s = 0.f;
    for (int j = part * seg; j < (part + 1) * seg; ++j) {
      if (labels[j] == li) {
        float d = zpos[j] - pi;
        s += __expf(-0.5f * d * d) * sinv[j];
      }
    }
    s += __shfl_xor(s, 1); s += __shfl_xor(s, 2);
    s += __shfl_xor(s, 4); s += __shfl_xor(s, 8);
    if (part == 0) tt[i] = s;
    return;
  }

  __shared__ __align__(16) ushort As[BM * BK];   // 16 KB, rows 128B (8 slots)
  __shared__ __align__(16) ushort Bs[BM * BK];   // 16 KB

  const int lane = tid & 63;
  const int wv = tid >> 6;        // 0..3
  const int wr = wv >> 1;         // wave row quadrant
  const int wc = wv & 1;          // wave col quadrant
  const int colq = lane & 15;
  const int laneg = lane >> 4;

  // 2D XCD swizzle (bijective): XCD (bid&7) owns tiles
  // rt in [(xcd>>2)*16, +16), ct in [(xcd&3)*8, +8)  -> 3 MB L2 footprint.
  const int xcd = bid & 7;
  const int w = bid >> 3;                 // 0..127 within XCD
  const int rt = (xcd >> 2) * 16 + (w >> 3);   // 0..31
  const int ct = (xcd & 3) * 8 + (w & 7);      // 0..31
  const int rowBase = rt * BM;
  const int colBase = ct * BM;

  // staging geometry (verbatim R4): 1 inst = 8 rows x 128B;
  // lane -> row lane>>3, slot lane&7; source slot pre-XORed with row.
  const int srow = lane >> 3;
  const int sslot = (lane & 7) ^ srow;

  f32x4 acc[4][4] = {};

  for (int kt = 0; kt < KSTEPS; ++kt) {
    // ---- stage A & B tiles (each wave: rows [wv*32, +32) of both) ----
#pragma unroll
    for (int q = 0; q < 4; ++q) {
      int rloc = wv * 32 + q * 8;
      async_copy16(zb + (size_t)(rowBase + rloc + srow) * D + kt * BK + sslot * 8,
                   (ushort*)As + rloc * BK);
      async_copy16(zb + (size_t)(colBase + rloc + srow) * D + kt * BK + sslot * 8,
                   (ushort*)Bs + rloc * BK);
    }
    __syncthreads();   // drains vmcnt: tiles resident

    // ---- compute: 2 k-substeps of 32 ----
#pragma unroll
    for (int kk = 0; kk < 2; ++kk) {
      bf16x8 a[4], b[4];
      const int slot = kk * 4 + laneg;
#pragma unroll
      for (int rf = 0; rf < 4; ++rf) {
        int r = wr * 64 + rf * 16 + colq;
        a[rf] = *reinterpret_cast<const bf16x8*>(
            reinterpret_cast<const char*>(As) + r * 128 + (slot ^ (r & 7)) * 16);
      }
#pragma unroll
      for (int cf = 0; cf < 4; ++cf) {
        int c = wc * 64 + cf * 16 + colq;
        b[cf] = *reinterpret_cast<const bf16x8*>(
            reinterpret_cast<const char*>(Bs) + c * 128 + (slot ^ (c & 7)) * 16);
      }
#pragma unroll
      for (int rf = 0; rf < 4; ++rf)
#pragma unroll
        for (int cf = 0; cf < 4; ++cf)
          acc[rf][cf] = __builtin_amdgcn_mfma_f32_16x16x32_bf16(a[rf], b[cf], acc[rf][cf], 0, 0, 0);
    }
    __syncthreads();   // LDS free for next K-tile
  }

  // ---- epilogue (verbatim R4) ----
  // C layout: col = lane&15, row = (lane>>4)*4 + reg  [m89 verified]
  const int wRowBase = rowBase + wr * 64;
  const int wColBase = colBase + wc * 64;
  const int rmodBase = (wRowBase >= N) ? wRowBase - N : wRowBase;
  const int cmodBase = (wColBase >= N) ? wColBase - N : wColBase;

  float rpos[16];
  unsigned rlab = 0;
#pragma unroll
  for (int rf = 0; rf < 4; ++rf)
#pragma unroll
    for (int rg = 0; rg < 4; ++rg) {
      int idx = rf * 4 + rg;
      int r = rmodBase + rf * 16 + laneg * 4 + rg;
      rpos[idx] = zpos[r];
      rlab |= ((unsigned)labels[r] & 3u) << (idx * 2);
    }

  float s_p[16], c_p[16];
#pragma unroll
  for (int i = 0; i < 16; ++i) { s_p[i] = 0.f; c_p[i] = 0.f; }

#pragma unroll
  for (int cf = 0; cf < 4; ++cf) {
    int jc = cmodBase + cf * 16 + colq;
    int lc = labels[jc];
    float pc = zpos[jc];
    float si = sinv[jc];
    int col = wColBase + cf * 16 + colq;
#pragma unroll
    for (int rf = 0; rf < 4; ++rf)
#pragma unroll
      for (int rg = 0; rg < 4; ++rg) {
        int idx = rf * 4 + rg;
        int row = wRowBase + rf * 16 + laneg * 4 + rg;
        float sim = acc[rf][cf][rg] * INV_T;
        bool dg = (row == col);
        if (dg) sim = -INF_VAL;
        s_p[idx] += __expf(sim - 10.f);        // exp(-1e8)==0: diag drops out
        int lr = (int)((rlab >> (idx * 2)) & 3u);
        if (lr == lc && !dg) {
          float d = rpos[idx] - pc;
          c_p[idx] = fmaf(__expf(-0.5f * d * d) * si, sim, c_p[idx]);
        }
      }
  }

  // reduce each row over the 16 lanes sharing it
#pragma unroll
  for (int idx = 0; idx < 16; ++idx) {
#pragma unroll
    for (int off = 1; off < 16; off <<= 1) {
      s_p[idx] += __shfl_xor(s_p[idx], off);
      c_p[idx] += __shfl_xor(c_p[idx], off);
    }
  }
  if (colq == 0) {
    int m = ct * 2 + wc;      // 64-wide column chunk index
#pragma unroll
    for (int rf = 0; rf < 4; ++rf)
#pragma unroll
      for (int rg = 0; rg < 4; ++rg) {
        int idx = rf * 4 + rg;
        int row = wRowBase + rf * 16 + laneg * 4 + rg;
        s_ws[(size_t)m * twoN + row] = s_p[idx];
        c_ws[(size_t)m * twoN + row] = c_p[idx];
      }
  }
}

// -------------------------------------------------------------------------
// Per-row combine + block partial sum (proven R8..R11, NCHUNK=64 slots).
// 64 blocks x 64 rows. partial[a] = cross_a - wsum_a*(10 + log(sum_m s_ws))
__global__ __launch_bounds__(256) void k_combine(const float* __restrict__ s_ws,
                                                 const float* __restrict__ c_ws,
                                                 const float* __restrict__ sinv,
                                                 const float* __restrict__ tt,
                                                 float* __restrict__ bsum, int N) {
  __shared__ float sS[4][64], sC[4][64];
  int b = blockIdx.x, t = threadIdx.x;
  int r = t & 63, g = t >> 6;
  int twoN = 2 * N;
  int a = b * 64 + r;
  float s = 0.f, c = 0.f;
  for (int k = 0; k < NCHUNK / 4; ++k) {
    int m = g * (NCHUNK / 4) + k;
    s += s_ws[(size_t)m * twoN + a];
    c += c_ws[(size_t)m * twoN + a];
  }
  sS[g][r] = s;
  sC[g][r] = c;
  __syncthreads();
  if (t < 64) {
    float st = sS[0][t] + sS[1][t] + sS[2][t] + sS[3][t];
    float ct = sC[0][t] + sC[1][t] + sC[2][t] + sC[3][t];
    int aa = b * 64 + t;
    int ir = (aa >= N) ? aa - N : aa;
    float lse = 10.f + logf(st);
    float wsum = 2.f * tt[ir] - sinv[ir];
    float p = ct - wsum * lse;
    p = wave_reduce_sum(p);
    if (t == 0) bsum[b] = p;
  }
}

// loss = (-1/N) * sum_b bsum[b]
__global__ __launch_bounds__(64) void k_final(const float* __restrict__ bsum,
                                              float* __restrict__ out, int N) {
  float s = bsum[threadIdx.x];
  s = wave_reduce_sum(s);
  if (threadIdx.x == 0) out[0] = (-1.0f / (float)N) * s;
}

extern "C" void kernel_launch(void* const* d_in, const int* in_sizes, int n_in,
                              void* d_out, int out_size, void* d_ws, size_t ws_size,
                              hipStream_t stream) {
  (void)n_in; (void)out_size; (void)ws_size;
  const float* zi = (const float*)d_in[0];
  const float* zj = (const float*)d_in[1];
  const int* labels = (const int*)d_in[2];
  const float* zpos = (const float*)d_in[3];
  float* out = (float*)d_out;

  const int N = in_sizes[2];       // 2048
  const int twoN = 2 * N;

  // workspace: zb bf16[2N*D] | sinv[N] | tt[N] | s_ws[64*2N] | c_ws[64*2N] | bsum[64]
  char* wsb = (char*)d_ws;
  ushort* zb = (ushort*)wsb;                              // 4 MB
  float* sinv = (float*)(wsb + (size_t)twoN * D * 2);
  float* tt = sinv + N;
  float* s_ws = tt + N;                                   // 1 MB
  float* c_ws = s_ws + (size_t)NCHUNK * twoN;             // 1 MB
  float* bsum = c_ws + (size_t)NCHUNK * twoN;

  k_prep<<<1024 + 2048, 256, 0, stream>>>(zi, zj, zb, labels, zpos, sinv, N);
  k_gemm<<<NGB + TTBLK, 256, 0, stream>>>(zb, labels, zpos, sinv, tt, s_ws, c_ws, N);
  k_combine<<<twoN / 64, 256, 0, stream>>>(s_ws, c_ws, sinv, tt, bsum, N);
  k_final<<<1, 64, 0, stream>>>(bsum, out, N);
}